// Round 2
// baseline (308.806 us; speedup 1.0000x reference)
//
#include <hip/hip_runtime.h>
#include <math.h>

// out[i][j] = | prod_w cos((x[i][w]+y[j][w])/2 + theta[w]) |
//           = | prod_w ( cA[w][i]*cB[w][j] - sA[w][i]*sB[w][j] ) |
// where (cA,sA) = sincos(x/2 + theta/2), (cB,sB) = sincos(y/2 + theta/2).
// RX(x)RX(th)=RX(x+th) -> product state; CNOT ladder is a fixed permutation P and
// the reference uses a plain (non-conjugated) bilinear form, so (Pa)·(Pb)=a·b.
//
// Structure: kernel 1 precomputes 16 trig planes (8192 floats each) into d_ws;
// kernel 2 is a barrier-free, LDS-free streaming kernel: 2048 blocks, each owns
// a 16-row stripe and walks 8 column-chunks of 256, A-trig pinned in registers.

#define N 8192        // rows of x and y (from in_sizes/4)
#define ROWS_PER_STRIPE 16
#define CHUNK 256     // cols per chunk (64 lanes * float4)
#define WALKERS 4     // column walkers per stripe
#define CHUNKS_PER_WALKER 8   // 4*8*256 = 8192 cols

// ws layout: planes of N floats.
//  [0..3]  = cos(x/2+th/2) per wire   [4..7]  = sin(x/2+th/2)
//  [8..11] = cos(y/2+th/2) per wire   [12..15]= sin(y/2+th/2)

__global__ __launch_bounds__(256) void qk_trig(
    const float* __restrict__ x, const float* __restrict__ y,
    const float* __restrict__ theta, float* __restrict__ ws)
{
    const int r = blockIdx.x * 256 + threadIdx.x;   // 0..2N-1
    const float th0 = 0.5f * theta[0];
    const float th1 = 0.5f * theta[1];
    const float th2 = 0.5f * theta[2];
    const float th3 = 0.5f * theta[3];

    const bool is_y = (r >= N);
    const int row = is_y ? (r - N) : r;
    const float4 v = ((const float4*)(is_y ? y : x))[row];
    float* base = ws + (is_y ? 8 * N : 0);

    float s, c;
    __sincosf(0.5f * v.x + th0, &s, &c); base[0 * N + row] = c; base[4 * N + row] = s;
    __sincosf(0.5f * v.y + th1, &s, &c); base[1 * N + row] = c; base[5 * N + row] = s;
    __sincosf(0.5f * v.z + th2, &s, &c); base[2 * N + row] = c; base[6 * N + row] = s;
    __sincosf(0.5f * v.w + th3, &s, &c); base[3 * N + row] = c; base[7 * N + row] = s;
}

__global__ __launch_bounds__(256) void qk_main(
    const float* __restrict__ ws, float* __restrict__ out)
{
    const int tid = threadIdx.x;
    const int tx = tid & 63;          // 4 consecutive cols per lane
    const int ty = tid >> 6;          // wave id -> 4 consecutive rows
    const int stripe = blockIdx.x >> 2;          // 0..511 (16-row stripes)
    const int cw = blockIdx.x & (WALKERS - 1);   // 0..3

    const int row0 = stripe * ROWS_PER_STRIPE + ty * 4;

    const float* xc = ws;
    const float* xs = ws + 4 * N;
    const float* yc = ws + 8 * N;
    const float* ys = ws + 12 * N;

    // A-trig for this thread's 4 rows: wave-uniform float4 loads, pinned in regs.
    float4 ac[4], as4[4];
    #pragma unroll
    for (int w = 0; w < 4; ++w) {
        ac[w]  = *(const float4*)&xc[w * N + row0];
        as4[w] = *(const float4*)&xs[w * N + row0];
    }
    const float cai[4][4] = {
        {ac[0].x, ac[0].y, ac[0].z, ac[0].w}, {ac[1].x, ac[1].y, ac[1].z, ac[1].w},
        {ac[2].x, ac[2].y, ac[2].z, ac[2].w}, {ac[3].x, ac[3].y, ac[3].z, ac[3].w}};
    const float sai[4][4] = {
        {as4[0].x, as4[0].y, as4[0].z, as4[0].w}, {as4[1].x, as4[1].y, as4[1].z, as4[1].w},
        {as4[2].x, as4[2].y, as4[2].z, as4[2].w}, {as4[3].x, as4[3].y, as4[3].z, as4[3].w}};

    #pragma unroll 1
    for (int k = 0; k < CHUNKS_PER_WALKER; ++k) {
        const int j0 = (cw * CHUNKS_PER_WALKER + k) * CHUNK + tx * 4;

        // B-trig for this thread's 4 cols: 8 coalesced dwordx4 loads (L2-hit).
        float4 bc[4], bs4[4];
        #pragma unroll
        for (int w = 0; w < 4; ++w) {
            bc[w]  = *(const float4*)&yc[w * N + j0];
            bs4[w] = *(const float4*)&ys[w * N + j0];
        }

        float acc[4][4];
        #pragma unroll
        for (int w = 0; w < 4; ++w) {
            const float cbj[4] = {bc[w].x, bc[w].y, bc[w].z, bc[w].w};
            const float sbj[4] = {bs4[w].x, bs4[w].y, bs4[w].z, bs4[w].w};
            #pragma unroll
            for (int i = 0; i < 4; ++i) {
                #pragma unroll
                for (int j = 0; j < 4; ++j) {
                    const float t = fmaf(cai[w][i], cbj[j], -(sai[w][i] * sbj[j]));
                    acc[i][j] = (w == 0) ? t : acc[i][j] * t;
                }
            }
        }

        #pragma unroll
        for (int i = 0; i < 4; ++i) {
            float4 o;
            o.x = fabsf(acc[i][0]);
            o.y = fabsf(acc[i][1]);
            o.z = fabsf(acc[i][2]);
            o.w = fabsf(acc[i][3]);
            *(float4*)&out[(size_t)(row0 + i) * N + j0] = o;
        }
    }
}

extern "C" void kernel_launch(void* const* d_in, const int* in_sizes, int n_in,
                              void* d_out, int out_size, void* d_ws, size_t ws_size,
                              hipStream_t stream) {
    const float* x     = (const float*)d_in[0];
    const float* y     = (const float*)d_in[1];
    const float* theta = (const float*)d_in[2];
    float* out = (float*)d_out;
    float* ws  = (float*)d_ws;

    // Kernel 1: 2N rows of trig -> 16 planes in ws (512 KB).
    qk_trig<<<(2 * N) / 256, 256, 0, stream>>>(x, y, theta, ws);

    // Kernel 2: 512 stripes * 4 walkers = 2048 blocks, barrier/LDS-free.
    qk_main<<<(N / ROWS_PER_STRIPE) * WALKERS, 256, 0, stream>>>(ws, out);
}

// Round 3
// 255.507 us; speedup vs baseline: 1.2086x; 1.2086x over previous
//
#include <hip/hip_runtime.h>
#include <math.h>

// out[i][j] = | prod_w cos((x[i][w]+y[j][w])/2 + theta[w]) |
//           = | prod_w ( cA[w][i]*cB[w][j] - sA[w][i]*sB[w][j] ) |
// (cA,sA) = sincos(x/2 + theta/2), (cB,sB) = sincos(y/2 + theta/2).
// RX(x)RX(th)=RX(x+th) -> product state; CNOT ladder is a fixed permutation P and
// the reference bilinear form is non-conjugated, so (Pa)·(Pb)=a·b — CNOTs cancel.
//
// R3 structure: trig precompute kernel -> 16 planes in d_ws; main kernel is
// R1's one-tile-per-block shape (16x256 tile, 16384 blocks) but loads trig
// global->registers: no LDS, no barrier, no sincos, no divergence in the tile
// kernel. Stores at block end drain overlapped with other resident blocks.

#define N 8192
#define BM 16    // rows per tile
#define BN 256   // cols per tile

// ws planes of N floats:
//  [0..3] cos(x/2+th/2)  [4..7] sin(x/2+th/2)
//  [8..11] cos(y/2+th/2) [12..15] sin(y/2+th/2)

__global__ __launch_bounds__(256) void qk_trig(
    const float* __restrict__ x, const float* __restrict__ y,
    const float* __restrict__ theta, float* __restrict__ ws)
{
    const int r = blockIdx.x * 256 + threadIdx.x;   // 0..2N-1
    const float th0 = 0.5f * theta[0];
    const float th1 = 0.5f * theta[1];
    const float th2 = 0.5f * theta[2];
    const float th3 = 0.5f * theta[3];

    const bool is_y = (r >= N);
    const int row = is_y ? (r - N) : r;
    const float4 v = ((const float4*)(is_y ? y : x))[row];
    float* base = ws + (is_y ? 8 * N : 0);

    float s, c;
    __sincosf(0.5f * v.x + th0, &s, &c); base[0 * N + row] = c; base[4 * N + row] = s;
    __sincosf(0.5f * v.y + th1, &s, &c); base[1 * N + row] = c; base[5 * N + row] = s;
    __sincosf(0.5f * v.z + th2, &s, &c); base[2 * N + row] = c; base[6 * N + row] = s;
    __sincosf(0.5f * v.w + th3, &s, &c); base[3 * N + row] = c; base[7 * N + row] = s;
}

__global__ __launch_bounds__(256) void qk_main(
    const float* __restrict__ ws, float* __restrict__ out)
{
    const int tid = threadIdx.x;
    const int tx = tid & 63;          // 4 consecutive cols per lane
    const int ty = tid >> 6;          // wave id -> 4 consecutive rows
    const int row0 = blockIdx.y * BM + ty * 4;
    const int j0   = blockIdx.x * BN + tx * 4;

    const float* xc = ws;
    const float* xs = ws + 4 * N;
    const float* yc = ws + 8 * N;
    const float* ys = ws + 12 * N;

    // B-trig: 8 coalesced dwordx4 loads (1 KB/wave each, L2-hit).
    float4 bc[4], bs4[4];
    #pragma unroll
    for (int w = 0; w < 4; ++w) {
        bc[w]  = *(const float4*)&yc[w * N + j0];
        bs4[w] = *(const float4*)&ys[w * N + j0];
    }
    // A-trig: wave-uniform float4 loads (single cacheline broadcast per wave).
    float4 ac[4], as4[4];
    #pragma unroll
    for (int w = 0; w < 4; ++w) {
        ac[w]  = *(const float4*)&xc[w * N + row0];
        as4[w] = *(const float4*)&xs[w * N + row0];
    }

    float acc[4][4];
    #pragma unroll
    for (int w = 0; w < 4; ++w) {
        const float cai[4] = {ac[w].x, ac[w].y, ac[w].z, ac[w].w};
        const float sai[4] = {as4[w].x, as4[w].y, as4[w].z, as4[w].w};
        const float cbj[4] = {bc[w].x, bc[w].y, bc[w].z, bc[w].w};
        const float sbj[4] = {bs4[w].x, bs4[w].y, bs4[w].z, bs4[w].w};
        #pragma unroll
        for (int i = 0; i < 4; ++i) {
            #pragma unroll
            for (int j = 0; j < 4; ++j) {
                const float t = fmaf(cai[i], cbj[j], -(sai[i] * sbj[j]));
                acc[i][j] = (w == 0) ? t : acc[i][j] * t;
            }
        }
    }

    // Coalesced float4 stores: 4 rows per thread, at block end (async drain).
    #pragma unroll
    for (int i = 0; i < 4; ++i) {
        float4 o;
        o.x = fabsf(acc[i][0]);
        o.y = fabsf(acc[i][1]);
        o.z = fabsf(acc[i][2]);
        o.w = fabsf(acc[i][3]);
        *(float4*)&out[(size_t)(row0 + i) * N + j0] = o;
    }
}

extern "C" void kernel_launch(void* const* d_in, const int* in_sizes, int n_in,
                              void* d_out, int out_size, void* d_ws, size_t ws_size,
                              hipStream_t stream) {
    const float* x     = (const float*)d_in[0];
    const float* y     = (const float*)d_in[1];
    const float* theta = (const float*)d_in[2];
    float* out = (float*)d_out;
    float* ws  = (float*)d_ws;

    qk_trig<<<(2 * N) / 256, 256, 0, stream>>>(x, y, theta, ws);

    dim3 grid(N / BN, N / BM);   // (32, 512) = 16384 blocks
    qk_main<<<grid, dim3(256), 0, stream>>>(ws, out);
}